// Round 15
// baseline (564.041 us; speedup 1.0000x reference)
//
#include <hip/hip_runtime.h>
#include <cstdint>

#define BATCH_ 2048
#define IN_    512
#define HID_   1024
#define NL_    30

typedef _Float16 h8 __attribute__((ext_vector_type(8)));
typedef _Float16 h4 __attribute__((ext_vector_type(4)));
typedef float f4 __attribute__((ext_vector_type(4)));

// ---------------------------------------------------------------------------
// global -> LDS direct staging (16B per lane)
// ---------------------------------------------------------------------------
__device__ __forceinline__ void gload_lds16(const void* g, void* l) {
  __builtin_amdgcn_global_load_lds(
      (const __attribute__((address_space(1))) uint32_t*)g,
      (__attribute__((address_space(3))) uint32_t*)l, 16, 0, 0);
}

// ---------------------------------------------------------------------------
// Generic fp16 NT MFMA GEMM over up to 3 (A,B) pass pairs (split-fp16 trick):
//   acc = sum_p A_p @ B_p^T      (prologue/epilogue GEMMs)
// Epilogues:
//   H_GH : oh = fp16(acc) ; if (row==col) dG[row] = acc   (G = W@W^T)
//   H_C  : oh = fp16(0.1*dG[col] - 1.2*acc)               (C matrix, fp16 out)
//   H_OUT: of = acc                                       (decode)
// ---------------------------------------------------------------------------
enum { H_GH = 0, H_C = 1, H_OUT = 2 };

template <int EPI>
__global__ __launch_bounds__(256, 4) void hgemm_nt(
    const _Float16* __restrict__ A0, const _Float16* __restrict__ B0,
    const _Float16* __restrict__ A1, const _Float16* __restrict__ B1,
    const _Float16* __restrict__ A2, const _Float16* __restrict__ B2,
    int npass, int ktpp,
    float* __restrict__ of, _Float16* __restrict__ oh, float* __restrict__ dG,
    int N, int K) {
  __shared__ char smem[2 * 16384];
  const int t = threadIdx.x;
  const int lane = t & 63;
  const int w = t >> 6;
  const int wm = w >> 1, wn = w & 1;
  const int m0 = blockIdx.y * 64, n0 = blockIdx.x * 64;

  int srow[2], scol[2];
#pragma unroll
  for (int s2 = 0; s2 < 2; ++s2) {
    int p = (w * 2 + s2) * 1024 + lane * 16;
    int row = p >> 7;
    int c = ((p >> 4) & 7) ^ (row & 7);
    srow[s2] = row;
    scol[s2] = c * 8;
  }

  auto selA = [&](int p) { return p == 0 ? A0 : (p == 1 ? A1 : A2); };
  auto selB = [&](int p) { return p == 0 ? B0 : (p == 1 ? B1 : B2); };

  auto stage = [&](int buf, const _Float16* Ab, const _Float16* Bb, int kt) {
#pragma unroll
    for (int s2 = 0; s2 < 2; ++s2) {
      int seg = w * 2 + s2;
      const _Float16* ga = Ab + (size_t)(m0 + srow[s2]) * K + kt * 64 + scol[s2];
      gload_lds16(ga, smem + buf * 16384 + seg * 1024);
      const _Float16* gb = Bb + (size_t)(n0 + srow[s2]) * K + kt * 64 + scol[s2];
      gload_lds16(gb, smem + buf * 16384 + 8192 + seg * 1024);
    }
  };

  f4 acc[2][2];
#pragma unroll
  for (int i = 0; i < 2; i++)
#pragma unroll
    for (int j = 0; j < 2; j++) acc[i][j] = (f4){0.f, 0.f, 0.f, 0.f};

  const int fr = lane & 15;
  const int kg = lane >> 4;

  const int NTtot = npass * ktpp;
  stage(0, selA(0), selB(0), 0);
  int cur = 0, p = 0, kk = 0;
  for (int tt = 0; tt < NTtot; ++tt) {
    __syncthreads();
    int pn = p, kn = kk + 1;
    if (kn == ktpp) { kn = 0; pn = p + 1; }
    if (tt + 1 < NTtot) stage(cur ^ 1, selA(pn), selB(pn), kn);
    const char* Ab = smem + cur * 16384;
    const char* Bb = smem + cur * 16384 + 8192;
#pragma unroll
    for (int ks = 0; ks < 2; ++ks) {
      h8 af[2], bf[2];
#pragma unroll
      for (int i = 0; i < 2; i++) {
        int row = wm * 32 + i * 16 + fr;
        int c = (ks * 4 + kg) ^ (row & 7);
        af[i] = *(const h8*)(Ab + row * 128 + c * 16);
      }
#pragma unroll
      for (int j = 0; j < 2; j++) {
        int row = wn * 32 + j * 16 + fr;
        int c = (ks * 4 + kg) ^ (row & 7);
        bf[j] = *(const h8*)(Bb + row * 128 + c * 16);
      }
#pragma unroll
      for (int i = 0; i < 2; i++)
#pragma unroll
        for (int j = 0; j < 2; j++)
          acc[i][j] =
              __builtin_amdgcn_mfma_f32_16x16x32_f16(af[i], bf[j], acc[i][j], 0, 0, 0);
    }
    __syncthreads();
    cur ^= 1; p = pn; kk = kn;
  }

  const int orow = (lane >> 4) * 4;
  const int ocol = lane & 15;
#pragma unroll
  for (int i = 0; i < 2; i++) {
#pragma unroll
    for (int j = 0; j < 2; j++) {
      int col = n0 + wn * 32 + j * 16 + ocol;
#pragma unroll
      for (int r = 0; r < 4; r++) {
        int row = m0 + wm * 32 + i * 16 + orow + r;
        size_t idx = (size_t)row * N + col;
        float v = acc[i][j][r];
        if constexpr (EPI == H_GH) {
          oh[idx] = (_Float16)v;
          if (row == col) dG[row] = v;
        }
        if constexpr (EPI == H_C) oh[idx] = (_Float16)(0.1f * dG[col] - 1.2f * v);
        if constexpr (EPI == H_OUT) of[idx] = v;
      }
    }
  }
}

// ---------------------------------------------------------------------------
// Iteration kernel: z_h = fp16( xth - step * (xth @ Gh^T + Cbh) )
// r6 skeleton with 5-BUFFER / ONE-BARRIER-PER-TWO-K-TILES pipeline:
//   tile t lives in buf t%5 (80KB LDS = exactly 2 blocks/CU).
//   iter kt (step 2): vmcnt(4)  -> tiles kt,kt+1 staged (kt+2 in flight)
//                     s_barrier -> also retires readers of tiles kt-2,kt-1
//                     stage kt+3,kt+4 (into bufs of kt-2,kt-1)
//                     compute kt, kt+1  (32 MFMA per iteration)
// Barrier count 16 -> 8 per block; MFMA order identical to r14.
// ---------------------------------------------------------------------------
__global__ __launch_bounds__(256, 2) void hmma_z(
    const _Float16* __restrict__ Ah, const _Float16* __restrict__ Bh,
    const _Float16* __restrict__ Cb, _Float16* __restrict__ Z,
    const float* __restrict__ step_p) {
  constexpr int K = HID_, N = HID_;
  constexpr int NT = K / 64;  // 16 (even)
  __shared__ char smem[5 * 16384];  // 5 x [A:8KB | B:8KB] = 80KB
  const int t = threadIdx.x;
  const int lane = t & 63;
  const int w = t >> 6;
  const int wm = w >> 1, wn = w & 1;

  // XCD-chunked swizzle: hw&7 = xcd owns 64 contiguous logical tiles
  const int hw = blockIdx.x;
  const int logical = (hw & 7) * 64 + (hw >> 3);
  const int m0 = (logical >> 4) * 64;   // 32 m-panels
  const int n0 = (logical & 15) * 64;   // 16 n-panels

  int srow[2], scol[2];
#pragma unroll
  for (int s2 = 0; s2 < 2; ++s2) {
    int p = (w * 2 + s2) * 1024 + lane * 16;
    int row = p >> 7;
    int c = ((p >> 4) & 7) ^ (row & 7);
    srow[s2] = row;
    scol[s2] = c * 8;
  }

#define STAGE(buf, kt)                                                        \
  do {                                                                        \
    _Pragma("unroll") for (int s2 = 0; s2 < 2; ++s2) {                        \
      int seg = w * 2 + s2;                                                   \
      gload_lds16(Ah + (size_t)(m0 + srow[s2]) * K + (kt) * 64 + scol[s2],    \
                  smem + (buf) * 16384 + seg * 1024);                         \
      gload_lds16(Bh + (size_t)(n0 + srow[s2]) * K + (kt) * 64 + scol[s2],    \
                  smem + (buf) * 16384 + 8192 + seg * 1024);                  \
    }                                                                         \
  } while (0)

  f4 acc[2][2];
#pragma unroll
  for (int i = 0; i < 2; i++)
#pragma unroll
    for (int j = 0; j < 2; j++) acc[i][j] = (f4){0.f, 0.f, 0.f, 0.f};

  const int fr = lane & 15;
  const int kg = lane >> 4;

  STAGE(0, 0);
  STAGE(1, 1);
  STAGE(2, 2);
  for (int kt = 0; kt < NT; kt += 2) {
    if (kt < NT - 2)
      asm volatile("s_waitcnt vmcnt(4)" ::: "memory");
    else
      asm volatile("s_waitcnt vmcnt(0)" ::: "memory");
    __builtin_amdgcn_sched_barrier(0);
    __builtin_amdgcn_s_barrier();
    __builtin_amdgcn_sched_barrier(0);
    if (kt + 3 < NT) STAGE((kt + 3) % 5, kt + 3);
    if (kt + 4 < NT) STAGE((kt + 4) % 5, kt + 4);
#pragma unroll
    for (int tt = 0; tt < 2; ++tt) {
      const char* Ab = smem + ((kt + tt) % 5) * 16384;
      const char* Bb = Ab + 8192;
#pragma unroll
      for (int ks = 0; ks < 2; ++ks) {
        h8 af[2], bf[2];
#pragma unroll
        for (int i = 0; i < 2; i++) {
          int row = wm * 32 + i * 16 + fr;
          int c = (ks * 4 + kg) ^ (row & 7);
          af[i] = *(const h8*)(Ab + row * 128 + c * 16);
        }
#pragma unroll
        for (int j = 0; j < 2; j++) {
          int row = wn * 32 + j * 16 + fr;
          int c = (ks * 4 + kg) ^ (row & 7);
          bf[j] = *(const h8*)(Bb + row * 128 + c * 16);
        }
#pragma unroll
        for (int i = 0; i < 2; i++)
#pragma unroll
          for (int j = 0; j < 2; j++)
            acc[i][j] = __builtin_amdgcn_mfma_f32_16x16x32_f16(
                af[i], bf[j], acc[i][j], 0, 0, 0);
      }
    }
  }
#undef STAGE

  // Epilogue: z = fp16( (float)xth - step*(acc + (float)Cbh) )
  const float stepv = *step_p;
  const int orow = (lane >> 4) * 4;
  const int ocol = lane & 15;
#pragma unroll
  for (int i = 0; i < 2; i++) {
#pragma unroll
    for (int j = 0; j < 2; j++) {
      int col = n0 + wn * 32 + j * 16 + ocol;
#pragma unroll
      for (int r = 0; r < 4; r++) {
        int row = m0 + wm * 32 + i * 16 + orow + r;
        size_t idx = (size_t)row * N + col;
        Z[idx] = (_Float16)((float)Ah[idx] -
                            stepv * (acc[i][j][r] + (float)Cb[idx]));
      }
    }
  }
}

// ---------------------------------------------------------------------------
// f32 -> (hi fp16, lo fp16) split, 4 elems/thread
// ---------------------------------------------------------------------------
__global__ __launch_bounds__(256) void split_hl(const float* __restrict__ s,
                                                _Float16* __restrict__ hi,
                                                _Float16* __restrict__ lo) {
  int i = blockIdx.x * blockDim.x + threadIdx.x;
  float4 v = ((const float4*)s)[i];
  h4 h, l;
  h[0] = (_Float16)v.x; l[0] = (_Float16)(v.x - (float)h[0]);
  h[1] = (_Float16)v.y; l[1] = (_Float16)(v.y - (float)h[1]);
  h[2] = (_Float16)v.z; l[2] = (_Float16)(v.z - (float)h[2]);
  h[3] = (_Float16)v.w; l[3] = (_Float16)(v.w - (float)h[3]);
  ((h4*)hi)[i] = h;
  ((h4*)lo)[i] = l;
}

// ---------------------------------------------------------------------------
// W [1024][512] f32 -> WT hi fp16 [512][1024]
// ---------------------------------------------------------------------------
__global__ __launch_bounds__(256) void transpose_h(
    const float* __restrict__ W, _Float16* __restrict__ WTh) {
  __shared__ float tile[32][33];
  int bx = blockIdx.x * 32;
  int by = blockIdx.y * 32;
  int tx = threadIdx.x, ty = threadIdx.y;
#pragma unroll
  for (int i = 0; i < 32; i += 8)
    tile[ty + i][tx] = W[(size_t)(by + ty + i) * IN_ + bx + tx];
  __syncthreads();
#pragma unroll
  for (int i = 0; i < 32; i += 8)
    WTh[(size_t)(bx + ty + i) * HID_ + by + tx] = (_Float16)tile[tx][ty + i];
}

// ---------------------------------------------------------------------------
// Sparsemax (Michelot exact simplex projection) + FISTA momentum.
// ONE WAVE PER ROW (16 f32/lane), shfl-only reductions, no LDS.
// SINGLE h8-mapped path; optional negstep scale (layer 0 reads Cbh).
// ---------------------------------------------------------------------------
__global__ __launch_bounds__(256) void sparsemax_w(
    const _Float16* __restrict__ zh, const float* __restrict__ negstep,
    _Float16* __restrict__ xoh, _Float16* __restrict__ xth, float mom) {
  const int lane = threadIdx.x & 63;
  const int row = blockIdx.x * 4 + (threadIdx.x >> 6);

  const float sc = negstep ? -(*negstep) : 1.f;
  float4 v[4];
  const h8* zr = (const h8*)(zh + (size_t)row * HID_);
#pragma unroll
  for (int i = 0; i < 2; i++) {
    h8 a = zr[lane + 64 * i];
    v[2 * i] = make_float4(sc * (float)a[0], sc * (float)a[1],
                           sc * (float)a[2], sc * (float)a[3]);
    v[2 * i + 1] = make_float4(sc * (float)a[4], sc * (float)a[5],
                               sc * (float)a[6], sc * (float)a[7]);
  }

  float s = 0.f;
#pragma unroll
  for (int i = 0; i < 4; i++) s += v[i].x + v[i].y + v[i].z + v[i].w;
#pragma unroll
  for (int o = 32; o; o >>= 1) s += __shfl_xor(s, o, 64);
  float tau = (s - 1.0f) * (1.0f / (float)HID_);

  int cprev = HID_ + 1024;
  for (int it = 0; it < 64; ++it) {
    float sp = 0.f, cp = 0.f;
#pragma unroll
    for (int i = 0; i < 4; i++) {
      if (v[i].x > tau) { sp += v[i].x; cp += 1.f; }
      if (v[i].y > tau) { sp += v[i].y; cp += 1.f; }
      if (v[i].z > tau) { sp += v[i].z; cp += 1.f; }
      if (v[i].w > tau) { sp += v[i].w; cp += 1.f; }
    }
#pragma unroll
    for (int o = 32; o; o >>= 1) {
      sp += __shfl_xor(sp, o, 64);
      cp += __shfl_xor(cp, o, 64);
    }
    int ci = (int)cp;
    tau = (sp - 1.0f) / cp;
    if (ci == cprev) break;
    cprev = ci;
  }

  h8* xo8 = (h8*)(xoh + (size_t)row * HID_);
  h8* xt8 = (h8*)(xth + (size_t)row * HID_);
#pragma unroll
  for (int i = 0; i < 2; i++) {
    float xn[8], xt[8];
    const float4 va = v[2 * i], vb = v[2 * i + 1];
    xn[0] = fmaxf(va.x - tau, 0.f); xn[1] = fmaxf(va.y - tau, 0.f);
    xn[2] = fmaxf(va.z - tau, 0.f); xn[3] = fmaxf(va.w - tau, 0.f);
    xn[4] = fmaxf(vb.x - tau, 0.f); xn[5] = fmaxf(vb.y - tau, 0.f);
    xn[6] = fmaxf(vb.z - tau, 0.f); xn[7] = fmaxf(vb.w - tau, 0.f);
    if (mom > 0.f) {
      h8 xo = xo8[lane + 64 * i];
#pragma unroll
      for (int e = 0; e < 8; ++e) xt[e] = xn[e] + mom * (xn[e] - (float)xo[e]);
    } else {
#pragma unroll
      for (int e = 0; e < 8; ++e) xt[e] = xn[e];
    }
    h8 nv, tv;
#pragma unroll
    for (int e = 0; e < 8; ++e) {
      nv[e] = (_Float16)xn[e];
      tv[e] = (_Float16)xt[e];
    }
    xo8[lane + 64 * i] = nv;
    xt8[lane + 64 * i] = tv;
  }
}

// ---------------------------------------------------------------------------
extern "C" void kernel_launch(void* const* d_in, const int* in_sizes, int n_in,
                              void* d_out, int out_size, void* d_ws, size_t ws_size,
                              hipStream_t stream) {
  (void)in_sizes; (void)n_in; (void)out_size; (void)ws_size;
  const float* y      = (const float*)d_in[0];  // [2048,512]
  const float* W      = (const float*)d_in[1];  // [1024,512]
  const float* step_p = (const float*)d_in[2];  // scalar
  float* out = (float*)d_out;                   // [2048,512]

  _Float16* ws = (_Float16*)d_ws;
  _Float16* zh  = ws;                        // 2M h (fp16 z)
  _Float16* Cbh = zh + 2097152;              // 2M h (fp16 C)
  float* dG = (float*)(Cbh + 2097152);       // 1024 f32 (pad 1024)
  _Float16* Gh  = (_Float16*)(dG + 1024);    // 1M h
  _Float16* yh  = Gh + 1048576;              // 1M h
  _Float16* yl  = yh + 1048576;              // 1M h
  _Float16* Wh  = yl + 1048576;              // 512K h
  _Float16* WTh = Wh + 524288;               // 512K h
  _Float16* Wl  = WTh + 524288;              // 512K h (scratch for split)
  _Float16* xoh = Wl + 524288;               // 2M h  (fp16 x_new state)
  // alias (lifetime-disjoint): x_tmp fp16 over yh+yl (dead after C-GEMM)
  _Float16* xth = yh;                        // 2M h

  dim3 blk(256);
  // prologue
  split_hl<<<dim3(BATCH_ * IN_ / 4 / 256), blk, 0, stream>>>(y, yh, yl);
  split_hl<<<dim3(HID_ * IN_ / 4 / 256), blk, 0, stream>>>(W, Wh, Wl);
  transpose_h<<<dim3(IN_ / 32, HID_ / 32), dim3(32, 8), 0, stream>>>(W, WTh);

  // Gh = fp16(Wh @ Wh^T), dG = diag (f32)
  hgemm_nt<H_GH><<<dim3(HID_ / 64, HID_ / 64), blk, 0, stream>>>(
      Wh, Wh, nullptr, nullptr, nullptr, nullptr, 1, IN_ / 64,
      nullptr, Gh, dG, HID_, IN_);
  // Cbh = fp16( 0.1*dG[n] - 1.2*(y @ W^T) )  via split-fp16, 2 passes
  hgemm_nt<H_C><<<dim3(HID_ / 64, BATCH_ / 64), blk, 0, stream>>>(
      yh, Wh, yl, Wh, nullptr, nullptr, 2, IN_ / 64,
      nullptr, Cbh, dG, HID_, IN_);

  // layer 0: z = -step*C folded into sparsemax (reads Cbh); mom = 0
  sparsemax_w<<<dim3(BATCH_ / 4), blk, 0, stream>>>(Cbh, step_p, xoh, xth, 0.f);

  for (int l = 1; l < NL_; ++l) {
    hmma_z<<<dim3(512), blk, 0, stream>>>(xth, Gh, Cbh, zh, step_p);
    float mom = (float)l / ((float)l + 3.0f);
    sparsemax_w<<<dim3(BATCH_ / 4), blk, 0, stream>>>(zh, nullptr, xoh, xth, mom);
  }

  // decode: out = x_new @ WT^T, 1-pass fp16 (x on simplex -> lo-terms ~1e-5)
  hgemm_nt<H_OUT><<<dim3(IN_ / 64, BATCH_ / 64), blk, 0, stream>>>(
      xoh, WTh, nullptr, nullptr, nullptr, nullptr, 1, HID_ / 64,
      out, nullptr, nullptr, IN_, HID_);
}

// Round 16
// 548.827 us; speedup vs baseline: 1.0277x; 1.0277x over previous
//
#include <hip/hip_runtime.h>
#include <cstdint>

#define BATCH_ 2048
#define IN_    512
#define HID_   1024
#define NL_    30

typedef _Float16 h8 __attribute__((ext_vector_type(8)));
typedef _Float16 h4 __attribute__((ext_vector_type(4)));
typedef float f4 __attribute__((ext_vector_type(4)));

// ---------------------------------------------------------------------------
// global -> LDS direct staging (16B per lane)
// ---------------------------------------------------------------------------
__device__ __forceinline__ void gload_lds16(const void* g, void* l) {
  __builtin_amdgcn_global_load_lds(
      (const __attribute__((address_space(1))) uint32_t*)g,
      (__attribute__((address_space(3))) uint32_t*)l, 16, 0, 0);
}

// ---------------------------------------------------------------------------
// Generic fp16 NT MFMA GEMM over up to 3 (A,B) pass pairs:
//   acc = sum_p A_p @ B_p^T      (prologue/epilogue GEMMs)
// Epilogues:
//   H_GH : oh = fp16(acc) ; if (row==col) dG[row] = acc   (G = W@W^T)
//   H_C  : oh = fp16(0.1*dG[col] - 1.2*acc)               (C matrix, fp16 out)
//   H_OUT: of = acc                                       (decode)
// ---------------------------------------------------------------------------
enum { H_GH = 0, H_C = 1, H_OUT = 2 };

template <int EPI>
__global__ __launch_bounds__(256, 4) void hgemm_nt(
    const _Float16* __restrict__ A0, const _Float16* __restrict__ B0,
    const _Float16* __restrict__ A1, const _Float16* __restrict__ B1,
    const _Float16* __restrict__ A2, const _Float16* __restrict__ B2,
    int npass, int ktpp,
    float* __restrict__ of, _Float16* __restrict__ oh, float* __restrict__ dG,
    int N, int K) {
  __shared__ char smem[2 * 16384];
  const int t = threadIdx.x;
  const int lane = t & 63;
  const int w = t >> 6;
  const int wm = w >> 1, wn = w & 1;
  const int m0 = blockIdx.y * 64, n0 = blockIdx.x * 64;

  int srow[2], scol[2];
#pragma unroll
  for (int s2 = 0; s2 < 2; ++s2) {
    int p = (w * 2 + s2) * 1024 + lane * 16;
    int row = p >> 7;
    int c = ((p >> 4) & 7) ^ (row & 7);
    srow[s2] = row;
    scol[s2] = c * 8;
  }

  auto selA = [&](int p) { return p == 0 ? A0 : (p == 1 ? A1 : A2); };
  auto selB = [&](int p) { return p == 0 ? B0 : (p == 1 ? B1 : B2); };

  auto stage = [&](int buf, const _Float16* Ab, const _Float16* Bb, int kt) {
#pragma unroll
    for (int s2 = 0; s2 < 2; ++s2) {
      int seg = w * 2 + s2;
      const _Float16* ga = Ab + (size_t)(m0 + srow[s2]) * K + kt * 64 + scol[s2];
      gload_lds16(ga, smem + buf * 16384 + seg * 1024);
      const _Float16* gb = Bb + (size_t)(n0 + srow[s2]) * K + kt * 64 + scol[s2];
      gload_lds16(gb, smem + buf * 16384 + 8192 + seg * 1024);
    }
  };

  f4 acc[2][2];
#pragma unroll
  for (int i = 0; i < 2; i++)
#pragma unroll
    for (int j = 0; j < 2; j++) acc[i][j] = (f4){0.f, 0.f, 0.f, 0.f};

  const int fr = lane & 15;
  const int kg = lane >> 4;

  const int NTtot = npass * ktpp;
  stage(0, selA(0), selB(0), 0);
  int cur = 0, p = 0, kk = 0;
  for (int tt = 0; tt < NTtot; ++tt) {
    __syncthreads();
    int pn = p, kn = kk + 1;
    if (kn == ktpp) { kn = 0; pn = p + 1; }
    if (tt + 1 < NTtot) stage(cur ^ 1, selA(pn), selB(pn), kn);
    const char* Ab = smem + cur * 16384;
    const char* Bb = smem + cur * 16384 + 8192;
#pragma unroll
    for (int ks = 0; ks < 2; ++ks) {
      h8 af[2], bf[2];
#pragma unroll
      for (int i = 0; i < 2; i++) {
        int row = wm * 32 + i * 16 + fr;
        int c = (ks * 4 + kg) ^ (row & 7);
        af[i] = *(const h8*)(Ab + row * 128 + c * 16);
      }
#pragma unroll
      for (int j = 0; j < 2; j++) {
        int row = wn * 32 + j * 16 + fr;
        int c = (ks * 4 + kg) ^ (row & 7);
        bf[j] = *(const h8*)(Bb + row * 128 + c * 16);
      }
#pragma unroll
      for (int i = 0; i < 2; i++)
#pragma unroll
        for (int j = 0; j < 2; j++)
          acc[i][j] =
              __builtin_amdgcn_mfma_f32_16x16x32_f16(af[i], bf[j], acc[i][j], 0, 0, 0);
    }
    __syncthreads();
    cur ^= 1; p = pn; kk = kn;
  }

  const int orow = (lane >> 4) * 4;
  const int ocol = lane & 15;
#pragma unroll
  for (int i = 0; i < 2; i++) {
#pragma unroll
    for (int j = 0; j < 2; j++) {
      int col = n0 + wn * 32 + j * 16 + ocol;
#pragma unroll
      for (int r = 0; r < 4; r++) {
        int row = m0 + wm * 32 + i * 16 + orow + r;
        size_t idx = (size_t)row * N + col;
        float v = acc[i][j][r];
        if constexpr (EPI == H_GH) {
          oh[idx] = (_Float16)v;
          if (row == col) dG[row] = v;
        }
        if constexpr (EPI == H_C) oh[idx] = (_Float16)(0.1f * dG[col] - 1.2f * v);
        if constexpr (EPI == H_OUT) of[idx] = v;
      }
    }
  }
}

// ---------------------------------------------------------------------------
// Iteration kernel (r14 structure VERBATIM — best verified: 557us):
//   z_h = fp16( xth - step * (xth @ Gh^T + Cbh) )
// 4-buffer / 3-ahead counted-vmcnt pipeline, one s_barrier per K-step,
// global_load_lds + both-sides XOR swizzle, XCD-chunked blockIdx, grid 512,
// 64KB LDS -> 2 blocks/CU.
// ---------------------------------------------------------------------------
__global__ __launch_bounds__(256, 2) void hmma_z(
    const _Float16* __restrict__ Ah, const _Float16* __restrict__ Bh,
    const _Float16* __restrict__ Cb, _Float16* __restrict__ Z,
    const float* __restrict__ step_p) {
  constexpr int K = HID_, N = HID_;
  constexpr int NT = K / 64;  // 16
  __shared__ char smem[4 * 16384];  // 4 x [A:8KB | B:8KB]
  const int t = threadIdx.x;
  const int lane = t & 63;
  const int w = t >> 6;
  const int wm = w >> 1, wn = w & 1;

  // XCD-chunked swizzle: hw&7 = xcd owns 64 contiguous logical tiles
  const int hw = blockIdx.x;
  const int logical = (hw & 7) * 64 + (hw >> 3);
  const int m0 = (logical >> 4) * 64;   // 32 m-panels
  const int n0 = (logical & 15) * 64;   // 16 n-panels

  int srow[2], scol[2];
#pragma unroll
  for (int s2 = 0; s2 < 2; ++s2) {
    int p = (w * 2 + s2) * 1024 + lane * 16;
    int row = p >> 7;
    int c = ((p >> 4) & 7) ^ (row & 7);
    srow[s2] = row;
    scol[s2] = c * 8;
  }

#define STAGE(buf, kt)                                                        \
  do {                                                                        \
    _Pragma("unroll") for (int s2 = 0; s2 < 2; ++s2) {                        \
      int seg = w * 2 + s2;                                                   \
      gload_lds16(Ah + (size_t)(m0 + srow[s2]) * K + (kt) * 64 + scol[s2],    \
                  smem + (buf) * 16384 + seg * 1024);                         \
      gload_lds16(Bh + (size_t)(n0 + srow[s2]) * K + (kt) * 64 + scol[s2],    \
                  smem + (buf) * 16384 + 8192 + seg * 1024);                  \
    }                                                                         \
  } while (0)

  f4 acc[2][2];
#pragma unroll
  for (int i = 0; i < 2; i++)
#pragma unroll
    for (int j = 0; j < 2; j++) acc[i][j] = (f4){0.f, 0.f, 0.f, 0.f};

  const int fr = lane & 15;
  const int kg = lane >> 4;

  STAGE(0, 0);
  STAGE(1, 1);
  STAGE(2, 2);
  for (int kt = 0; kt < NT; ++kt) {
    if (kt < NT - 2)
      asm volatile("s_waitcnt vmcnt(8)" ::: "memory");
    else if (kt == NT - 2)
      asm volatile("s_waitcnt vmcnt(4)" ::: "memory");
    else
      asm volatile("s_waitcnt vmcnt(0)" ::: "memory");
    __builtin_amdgcn_sched_barrier(0);
    __builtin_amdgcn_s_barrier();
    __builtin_amdgcn_sched_barrier(0);
    if (kt + 3 < NT) STAGE((kt + 3) & 3, kt + 3);
    const char* Ab = smem + (kt & 3) * 16384;
    const char* Bb = Ab + 8192;
#pragma unroll
    for (int ks = 0; ks < 2; ++ks) {
      h8 af[2], bf[2];
#pragma unroll
      for (int i = 0; i < 2; i++) {
        int row = wm * 32 + i * 16 + fr;
        int c = (ks * 4 + kg) ^ (row & 7);
        af[i] = *(const h8*)(Ab + row * 128 + c * 16);
      }
#pragma unroll
      for (int j = 0; j < 2; j++) {
        int row = wn * 32 + j * 16 + fr;
        int c = (ks * 4 + kg) ^ (row & 7);
        bf[j] = *(const h8*)(Bb + row * 128 + c * 16);
      }
#pragma unroll
      for (int i = 0; i < 2; i++)
#pragma unroll
        for (int j = 0; j < 2; j++)
          acc[i][j] =
              __builtin_amdgcn_mfma_f32_16x16x32_f16(af[i], bf[j], acc[i][j], 0, 0, 0);
    }
  }
#undef STAGE

  // Epilogue: z = fp16( (float)xth - step*(acc + (float)Cbh) )
  const float stepv = *step_p;
  const int orow = (lane >> 4) * 4;
  const int ocol = lane & 15;
#pragma unroll
  for (int i = 0; i < 2; i++) {
#pragma unroll
    for (int j = 0; j < 2; j++) {
      int col = n0 + wn * 32 + j * 16 + ocol;
#pragma unroll
      for (int r = 0; r < 4; r++) {
        int row = m0 + wm * 32 + i * 16 + orow + r;
        size_t idx = (size_t)row * N + col;
        Z[idx] = (_Float16)((float)Ah[idx] -
                            stepv * (acc[i][j][r] + (float)Cb[idx]));
      }
    }
  }
}

// ---------------------------------------------------------------------------
// f32 -> fp16 convert, 4 elems/thread (hi-only; split no longer needed)
// ---------------------------------------------------------------------------
__global__ __launch_bounds__(256) void f2h(const float* __restrict__ s,
                                           _Float16* __restrict__ d) {
  int i = blockIdx.x * blockDim.x + threadIdx.x;
  float4 v = ((const float4*)s)[i];
  h4 h;
  h[0] = (_Float16)v.x; h[1] = (_Float16)v.y;
  h[2] = (_Float16)v.z; h[3] = (_Float16)v.w;
  ((h4*)d)[i] = h;
}

// ---------------------------------------------------------------------------
// W [1024][512] f32 -> WT fp16 [512][1024]
// ---------------------------------------------------------------------------
__global__ __launch_bounds__(256) void transpose_h(
    const float* __restrict__ W, _Float16* __restrict__ WTh) {
  __shared__ float tile[32][33];
  int bx = blockIdx.x * 32;
  int by = blockIdx.y * 32;
  int tx = threadIdx.x, ty = threadIdx.y;
#pragma unroll
  for (int i = 0; i < 32; i += 8)
    tile[ty + i][tx] = W[(size_t)(by + ty + i) * IN_ + bx + tx];
  __syncthreads();
#pragma unroll
  for (int i = 0; i < 32; i += 8)
    WTh[(size_t)(bx + ty + i) * HID_ + by + tx] = (_Float16)tile[tx][ty + i];
}

// ---------------------------------------------------------------------------
// Sparsemax (Michelot exact simplex projection) + FISTA momentum.
// ONE WAVE PER ROW (16 f32/lane), shfl-only reductions, no LDS.
// SINGLE h8-mapped path; optional negstep scale (layer 0 reads Cbh).
// ---------------------------------------------------------------------------
__global__ __launch_bounds__(256) void sparsemax_w(
    const _Float16* __restrict__ zh, const float* __restrict__ negstep,
    _Float16* __restrict__ xoh, _Float16* __restrict__ xth, float mom) {
  const int lane = threadIdx.x & 63;
  const int row = blockIdx.x * 4 + (threadIdx.x >> 6);

  const float sc = negstep ? -(*negstep) : 1.f;
  float4 v[4];
  const h8* zr = (const h8*)(zh + (size_t)row * HID_);
#pragma unroll
  for (int i = 0; i < 2; i++) {
    h8 a = zr[lane + 64 * i];
    v[2 * i] = make_float4(sc * (float)a[0], sc * (float)a[1],
                           sc * (float)a[2], sc * (float)a[3]);
    v[2 * i + 1] = make_float4(sc * (float)a[4], sc * (float)a[5],
                               sc * (float)a[6], sc * (float)a[7]);
  }

  float s = 0.f;
#pragma unroll
  for (int i = 0; i < 4; i++) s += v[i].x + v[i].y + v[i].z + v[i].w;
#pragma unroll
  for (int o = 32; o; o >>= 1) s += __shfl_xor(s, o, 64);
  float tau = (s - 1.0f) * (1.0f / (float)HID_);

  int cprev = HID_ + 1024;
  for (int it = 0; it < 64; ++it) {
    float sp = 0.f, cp = 0.f;
#pragma unroll
    for (int i = 0; i < 4; i++) {
      if (v[i].x > tau) { sp += v[i].x; cp += 1.f; }
      if (v[i].y > tau) { sp += v[i].y; cp += 1.f; }
      if (v[i].z > tau) { sp += v[i].z; cp += 1.f; }
      if (v[i].w > tau) { sp += v[i].w; cp += 1.f; }
    }
#pragma unroll
    for (int o = 32; o; o >>= 1) {
      sp += __shfl_xor(sp, o, 64);
      cp += __shfl_xor(cp, o, 64);
    }
    int ci = (int)cp;
    tau = (sp - 1.0f) / cp;
    if (ci == cprev) break;
    cprev = ci;
  }

  h8* xo8 = (h8*)(xoh + (size_t)row * HID_);
  h8* xt8 = (h8*)(xth + (size_t)row * HID_);
#pragma unroll
  for (int i = 0; i < 2; i++) {
    float xn[8], xt[8];
    const float4 va = v[2 * i], vb = v[2 * i + 1];
    xn[0] = fmaxf(va.x - tau, 0.f); xn[1] = fmaxf(va.y - tau, 0.f);
    xn[2] = fmaxf(va.z - tau, 0.f); xn[3] = fmaxf(va.w - tau, 0.f);
    xn[4] = fmaxf(vb.x - tau, 0.f); xn[5] = fmaxf(vb.y - tau, 0.f);
    xn[6] = fmaxf(vb.z - tau, 0.f); xn[7] = fmaxf(vb.w - tau, 0.f);
    if (mom > 0.f) {
      h8 xo = xo8[lane + 64 * i];
#pragma unroll
      for (int e = 0; e < 8; ++e) xt[e] = xn[e] + mom * (xn[e] - (float)xo[e]);
    } else {
#pragma unroll
      for (int e = 0; e < 8; ++e) xt[e] = xn[e];
    }
    h8 nv, tv;
#pragma unroll
    for (int e = 0; e < 8; ++e) {
      nv[e] = (_Float16)xn[e];
      tv[e] = (_Float16)xt[e];
    }
    xo8[lane + 64 * i] = nv;
    xt8[lane + 64 * i] = tv;
  }
}

// ---------------------------------------------------------------------------
extern "C" void kernel_launch(void* const* d_in, const int* in_sizes, int n_in,
                              void* d_out, int out_size, void* d_ws, size_t ws_size,
                              hipStream_t stream) {
  (void)in_sizes; (void)n_in; (void)out_size; (void)ws_size;
  const float* y      = (const float*)d_in[0];  // [2048,512]
  const float* W      = (const float*)d_in[1];  // [1024,512]
  const float* step_p = (const float*)d_in[2];  // scalar
  float* out = (float*)d_out;                   // [2048,512]

  _Float16* ws = (_Float16*)d_ws;
  _Float16* zh  = ws;                        // 2M h (fp16 z)
  _Float16* Cbh = zh + 2097152;              // 2M h (fp16 C)
  float* dG = (float*)(Cbh + 2097152);       // 1024 f32 (pad 1024)
  _Float16* Gh  = (_Float16*)(dG + 1024);    // 1M h
  _Float16* yh  = Gh + 1048576;              // 1M h
  _Float16* Wh  = yh + 1048576;              // 512K h
  _Float16* WTh = Wh + 524288;               // 512K h
  _Float16* xoh = WTh + 524288;              // 2M h (fp16 x_new state)
  _Float16* xth = xoh + 2097152;             // 2M h (fp16 x_tmp)

  dim3 blk(256);
  // prologue: fp16 converts (single-pass C makes lo-parts unnecessary)
  f2h<<<dim3(BATCH_ * IN_ / 4 / 256), blk, 0, stream>>>(y, yh);
  f2h<<<dim3(HID_ * IN_ / 4 / 256), blk, 0, stream>>>(W, Wh);
  transpose_h<<<dim3(IN_ / 32, HID_ / 32), dim3(32, 8), 0, stream>>>(W, WTh);

  // Gh = fp16(Wh @ Wh^T), dG = diag (f32)
  hgemm_nt<H_GH><<<dim3(HID_ / 64, HID_ / 64), blk, 0, stream>>>(
      Wh, Wh, nullptr, nullptr, nullptr, nullptr, 1, IN_ / 64,
      nullptr, Gh, dG, HID_, IN_);
  // Cbh = fp16( 0.1*dG[n] - 1.2*(yh @ Wh^T) )  — single pass (split-fp16
  // corrections ~3.6e-4 are at the same scale as the fp16-C rounding)
  hgemm_nt<H_C><<<dim3(HID_ / 64, BATCH_ / 64), blk, 0, stream>>>(
      yh, Wh, nullptr, nullptr, nullptr, nullptr, 1, IN_ / 64,
      nullptr, Cbh, dG, HID_, IN_);

  // layer 0: z = -step*C folded into sparsemax (reads Cbh); mom = 0
  sparsemax_w<<<dim3(BATCH_ / 4), blk, 0, stream>>>(Cbh, step_p, xoh, xth, 0.f);

  for (int l = 1; l < NL_; ++l) {
    hmma_z<<<dim3(512), blk, 0, stream>>>(xth, Gh, Cbh, zh, step_p);
    float mom = (float)l / ((float)l + 3.0f);
    sparsemax_w<<<dim3(BATCH_ / 4), blk, 0, stream>>>(zh, nullptr, xoh, xth, mom);
  }

  // decode: out = x_new @ WT^T, 1-pass fp16 (x on simplex -> lo-terms ~1e-5)
  hgemm_nt<H_OUT><<<dim3(IN_ / 64, BATCH_ / 64), blk, 0, stream>>>(
      xoh, WTh, nullptr, nullptr, nullptr, nullptr, 1, HID_ / 64,
      out, nullptr, nullptr, IN_, HID_);
}